// Round 5
// baseline (379.152 us; speedup 1.0000x reference)
//
#include <hip/hip_runtime.h>

typedef _Float16 f16;
typedef _Float16 f16x4 __attribute__((ext_vector_type(4)));
typedef _Float16 f16x8 __attribute__((ext_vector_type(8)));
typedef float f32x4 __attribute__((ext_vector_type(4)));

#define TPB  384           // 6 waves
#define NWIN 8             // windows per block
#define NTOKR 72           // real tokens per block
#define MT   5             // M-tiles (80 rows, tokens 72..79 are zero pad)
#define XS   200           // Xh row stride (halves): 400B = 25x16B
#define QS   40            // Qh/Kh/AOh row stride: 80B = 5x16B
#define VS   136           // Vt2 row stride: 272B = 17x16B
#define PS   40            // fallback P scratch row stride

#define HAVE_MFMA16 __has_builtin(__builtin_amdgcn_mfma_f32_16x16x16f16)

__global__ __launch_bounds__(TPB, 4) void lsa_mfma4(
    const float* __restrict__ x, const float* __restrict__ Wqkv,
    const float* __restrict__ Wproj, const float* __restrict__ bproj,
    float* __restrict__ out)
{
    __shared__ f16 Xh[80 * XS];      // 32000 B (rows 72..79 zeroed)
    __shared__ f16 Qh[80 * QS];      // 6400 B
    __shared__ f16 Kh[80 * QS];      // 6400 B
    __shared__ f16 Vt2[32 * VS];     // 8704 B (slots 9..15 per window stay zero)
    __shared__ f16 AOh[80 * QS];     // 6400 B (rows 72..79 zeroed once)
#if !HAVE_MFMA16
    __shared__ f16 Ps[6 * 16 * PS];  // 7680 B (fallback only)
#endif

    const int tid  = threadIdx.x;
    const int lane = tid & 63;
    const int w    = tid >> 6;      // wave 0..5 = channel-tile (QKV) / N-pair (proj)
    const int l15  = lane & 15;
    const int lg   = lane >> 4;     // 0..3

    // ---- geometry: 8 windows per block (never straddles batch / row-group) ----
    const int  bb    = blockIdx.x / 1536;
    const int  gbase = (blockIdx.x % 1536) * NWIN;
    const long rb0   = (long)bb * 110592 + (long)(gbase / 96) * 864 + (long)(gbase % 96) * 3;

    // ---- phase 0: X -> LDS fp16; zero pads ----
    for (int idx = tid; idx < NTOKR * 48; idx += TPB) {   // 9 exact iters
        int t = idx / 48, c4 = idx % 48;
        int wi = t / 9, q = t - 9 * wi;
        long grow = rb0 + wi * 3 + (q / 3) * 288 + (q % 3);
        float4 xv = ((const float4*)x)[grow * 48 + c4];
        union { f16 h[4]; ushort4 u; } tmp;
        tmp.h[0] = (f16)xv.x; tmp.h[1] = (f16)xv.y; tmp.h[2] = (f16)xv.z; tmp.h[3] = (f16)xv.w;
        *(ushort4*)&Xh[t * XS + c4 * 4] = tmp.u;
    }
    {
        int4 z = {0, 0, 0, 0};
        // Xh pad rows 72..79: 8*200*2 B = 200 int4
        for (int i2 = tid; i2 < 200; i2 += TPB) ((int4*)&Xh[72 * XS])[i2] = z;
        // AOh pad rows 72..79: 8*40*2 B = 40 int4
        if (tid < 40) ((int4*)&AOh[72 * QS])[tid] = z;
        // Vt2 fully zero (slots 9..15 per window must stay 0 forever)
        for (int i2 = tid; i2 < (32 * VS * 2) / 16; i2 += TPB) ((int4*)Vt2)[i2] = z;
#if !HAVE_MFMA16
        for (int i2 = tid; i2 < (6 * 16 * PS * 2) / 16; i2 += TPB) ((int4*)Ps)[i2] = z;
#endif
    }

    f32x4 pacc[MT][2];
    #pragma unroll
    for (int a = 0; a < MT; ++a) {
        pacc[a][0] = (f32x4){0.f, 0.f, 0.f, 0.f};
        pacc[a][1] = (f32x4){0.f, 0.f, 0.f, 0.f};
    }

    __syncthreads();

    const float4* Wq4 = (const float4*)Wqkv;
    const float4* Wp4 = (const float4*)Wproj;

    const int grp  = w >> 1;                 // 0=Q,1=K,2=V
    const int dloc = (w & 1) * 16;           // channel-tile offset within the 32
    const long wqrow = (long)(grp * 192 + (w & 1) * 16 + l15) * 48;  // + h*32*48 later

    for (int h = 0; h < 6; ++h) {
        // ---- QKV A-fragments straight from global (L2-resident weights) ----
        f16x8 af6[6];
        {
            const long rbase = wqrow + (long)h * 32 * 48;
            #pragma unroll
            for (int kk = 0; kk < 6; ++kk) {
                float4 wa = Wq4[rbase + kk * 8 + 2 * lg];
                float4 wb = Wq4[rbase + kk * 8 + 2 * lg + 1];
                f16x8 t;
                t[0] = (f16)wa.x; t[1] = (f16)wa.y; t[2] = (f16)wa.z; t[3] = (f16)wa.w;
                t[4] = (f16)wb.x; t[5] = (f16)wb.y; t[6] = (f16)wb.z; t[7] = (f16)wb.w;
                af6[kk] = t;
            }
        }

        // ---- QKV GEMM: A = W rows (16 channels, this wave), B = X tokens ----
        f32x4 qacc[MT];
        #pragma unroll
        for (int t = 0; t < MT; ++t) qacc[t] = (f32x4){0.f, 0.f, 0.f, 0.f};
        #pragma unroll
        for (int kk = 0; kk < 6; ++kk) {
            #pragma unroll
            for (int t = 0; t < MT; ++t) {
                f16x8 bf = *(const f16x8*)&Xh[(16 * t + l15) * XS + kk * 32 + lg * 8];
                qacc[t] = __builtin_amdgcn_mfma_f32_16x16x32_f16(af6[kk], bf, qacc[t], 0, 0, 0);
            }
        }
        // scatter: lane holds channels dloc+4lg..+3 of token 16t+l15
        #pragma unroll
        for (int t = 0; t < MT; ++t) {
            const int token = 16 * t + l15;
            f16x4 ph;
            ph[0] = (f16)qacc[t][0]; ph[1] = (f16)qacc[t][1];
            ph[2] = (f16)qacc[t][2]; ph[3] = (f16)qacc[t][3];
            if (grp == 0) {
                *(f16x4*)&Qh[token * QS + dloc + 4 * lg] = ph;
            } else if (grp == 1) {
                *(f16x4*)&Kh[token * QS + dloc + 4 * lg] = ph;
            } else {
                const int d0 = dloc + 4 * lg;
                int wi = token / 9, qq = token - 9 * wi;
                #pragma unroll
                for (int r = 0; r < 4; ++r)
                    Vt2[(d0 + r) * VS + 16 * wi + qq] = ph[r];
            }
        }
        __syncthreads();   // B: Q/K/V ready

        // ---- issue Wproj fragment loads early (used after barrier C) ----
        float4 wpv[4];
        #pragma unroll
        for (int bq = 0; bq < 2; ++bq) {
            const long prow = (long)(16 * (2 * w + bq) + l15) * 48 + h * 8 + 2 * lg;
            wpv[2 * bq]     = Wp4[prow];
            wpv[2 * bq + 1] = Wp4[prow + 1];
        }

        // ---- attention: scores (A=K, B=Q) -> in-register softmax -> PV (A=V, B=P) ----
        for (int wi = w; wi < NWIN; wi += 6) {
            f16x8 ak = *(const f16x8*)&Kh[(9 * wi + l15) * QS + lg * 8];
            f16x8 aq = *(const f16x8*)&Qh[(9 * wi + l15) * QS + lg * 8];
            f32x4 s = (f32x4){0.f, 0.f, 0.f, 0.f};
            s = __builtin_amdgcn_mfma_f32_16x16x32_f16(ak, aq, s, 0, 0, 0);
            // lane holds S[k = 4lg+r][q = l15]
            float lgt[4];
            float mx = -1e30f;
            #pragma unroll
            for (int r = 0; r < 4; ++r) {
                int kx = 4 * lg + r;
                lgt[r] = (kx < 9) ? s[r] * 0.17677669529663687f : -1e30f;
                mx = fmaxf(mx, lgt[r]);
            }
            mx = fmaxf(mx, __shfl_xor(mx, 16));
            mx = fmaxf(mx, __shfl_xor(mx, 32));
            float e[4], sum = 0.f;
            #pragma unroll
            for (int r = 0; r < 4; ++r) {
                int kx = 4 * lg + r;
                e[r] = (kx < 9) ? __expf(lgt[r] - mx) : 0.f;
                sum += e[r];
            }
            sum += __shfl_xor(sum, 16);
            sum += __shfl_xor(sum, 32);
            float inv = 1.0f / sum;
            f16x4 p;
            p[0] = (f16)(e[0] * inv); p[1] = (f16)(e[1] * inv);
            p[2] = (f16)(e[2] * inv); p[3] = (f16)(e[3] * inv);
#if HAVE_MFMA16
            #pragma unroll
            for (int dt = 0; dt < 2; ++dt) {
                f16x4 av = *(const f16x4*)&Vt2[(dt * 16 + l15) * VS + 16 * wi + 4 * lg];
                f32x4 o = (f32x4){0.f, 0.f, 0.f, 0.f};
                o = __builtin_amdgcn_mfma_f32_16x16x16f16(av, p, o, 0, 0, 0);
                if (l15 < 9) {
                    f16x4 oh;
                    oh[0] = (f16)o[0]; oh[1] = (f16)o[1]; oh[2] = (f16)o[2]; oh[3] = (f16)o[3];
                    *(f16x4*)&AOh[(9 * wi + l15) * QS + dt * 16 + 4 * lg] = oh;
                }
            }
#else
            {
                f16* myPs = &Ps[w * 16 * PS];
                #pragma unroll
                for (int r = 0; r < 4; ++r) myPs[l15 * PS + 4 * lg + r] = p[r];
                f16x8 pb = *(const f16x8*)&myPs[l15 * PS + 8 * lg];  // k 16..31 zero
                #pragma unroll
                for (int dt = 0; dt < 2; ++dt) {
                    f16x8 av8 = *(const f16x8*)&Vt2[(dt * 16 + l15) * VS + 16 * wi + 8 * lg];
                    f32x4 o = (f32x4){0.f, 0.f, 0.f, 0.f};
                    o = __builtin_amdgcn_mfma_f32_16x16x32_f16(av8, pb, o, 0, 0, 0);
                    if (l15 < 9) {
                        f16x4 oh;
                        oh[0] = (f16)o[0]; oh[1] = (f16)o[1]; oh[2] = (f16)o[2]; oh[3] = (f16)o[3];
                        *(f16x4*)&AOh[(9 * wi + l15) * QS + dt * 16 + 4 * lg] = oh;
                    }
                }
            }
#endif
        }
        __syncthreads();   // C: AOh ready

        // ---- proj partial: pacc += AO_h(80x32) @ Wproj_h(32 cols of head h)^T ----
        {
            f16x8 bw[2];
            #pragma unroll
            for (int bq = 0; bq < 2; ++bq) {
                f16x8 t;
                t[0] = (f16)wpv[2*bq].x; t[1] = (f16)wpv[2*bq].y;
                t[2] = (f16)wpv[2*bq].z; t[3] = (f16)wpv[2*bq].w;
                t[4] = (f16)wpv[2*bq+1].x; t[5] = (f16)wpv[2*bq+1].y;
                t[6] = (f16)wpv[2*bq+1].z; t[7] = (f16)wpv[2*bq+1].w;
                bw[bq] = t;
            }
            #pragma unroll
            for (int a = 0; a < MT; ++a) {
                f16x8 aof = *(const f16x8*)&AOh[(16 * a + l15) * QS + lg * 8];
                #pragma unroll
                for (int bq = 0; bq < 2; ++bq)
                    pacc[a][bq] = __builtin_amdgcn_mfma_f32_16x16x32_f16(aof, bw[bq], pacc[a][bq], 0, 0, 0);
            }
        }
        __syncthreads();   // D: Qh/Kh/Vt2/AOh free for next head
    }

    // ---- epilogue: pacc + bias -> out ----
    float bv[2];
    bv[0] = bproj[16 * (2 * w + 0) + l15];
    bv[1] = bproj[16 * (2 * w + 1) + l15];
    #pragma unroll
    for (int a = 0; a < MT; ++a) {
        #pragma unroll
        for (int r = 0; r < 4; ++r) {
            int t = 16 * a + lg * 4 + r;
            if (t < NTOKR) {
                int wi = t / 9, q = t - 9 * wi;
                long grow = rb0 + wi * 3 + (q / 3) * 288 + (q % 3);
                float* dst = out + grow * 192;
                dst[16 * (2 * w + 0) + l15] = pacc[a][0][r] + bv[0];
                dst[16 * (2 * w + 1) + l15] = pacc[a][1][r] + bv[1];
            }
        }
    }
}

extern "C" void kernel_launch(void* const* d_in, const int* in_sizes, int n_in,
                              void* d_out, int out_size, void* d_ws, size_t ws_size,
                              hipStream_t stream) {
    const float* x     = (const float*)d_in[0];
    const float* Wqkv  = (const float*)d_in[1];
    const float* Wproj = (const float*)d_in[2];
    const float* bproj = (const float*)d_in[3];
    float* out = (float*)d_out;
    // 24576 windows total, 8 per block
    lsa_mfma4<<<3072, TPB, 0, stream>>>(x, Wqkv, Wproj, bproj, out);
}